// Round 3
// baseline (345.757 us; speedup 1.0000x reference)
//
#include <hip/hip_runtime.h>
#include <hip/hip_bf16.h>
#include <math.h>

#define M 256
#define D 768
#define D4 (D/4)          // 192
#define THRESH 0.3
#define EPS 1e-8

typedef float vfloat4 __attribute__((ext_vector_type(4)));

// Workspace layout (floats):
#define WS_SM    0      // [256] row sums of mem
#define WS_NM2   256    // [256] row sumsq
#define WS_KX    512    // [256] dot(mem_i, x)
#define WS_MASK  768    // [256] mask (written redundantly by all k3 blocks)
#define WS_SX    1024
#define WS_NX2   1025
#define WS_MEMT  2048                 // [D*M] mem transposed, float4-chunked:
                                      // element (d,r) at (d>>2)*1024 + r*4 + (d&3)
#define WS_ST    (2048 + D * M)       // [M*M] sT[i*M + a] = s[a,i]

// ---- K1: per-row stats (blocks 0..255) + x stats (block 256) + chunked transpose ----
__global__ __launch_bounds__(256) void k1_stats_transpose(const float* __restrict__ x,
                                                          const float* __restrict__ mem,
                                                          float* __restrict__ ws) {
    const int r = blockIdx.x;
    const int t = threadIdx.x;
    const float* row = (r < M) ? (mem + (size_t)r * D) : x;

    double s = 0.0, sq = 0.0, dt = 0.0;
    for (int d = t; d < D; d += 256) {
        float mf = row[d];
        double m = (double)mf;
        double xv = (double)x[d];
        s += m; sq += m * m; dt += m * xv;
        if (r < M) ws[WS_MEMT + (d >> 2) * (M * 4) + r * 4 + (d & 3)] = mf;
    }
    __shared__ double sh0[256], sh1[256], sh2[256];
    sh0[t] = s; sh1[t] = sq; sh2[t] = dt;
    __syncthreads();
    for (int k = 128; k > 0; k >>= 1) {
        if (t < k) { sh0[t] += sh0[t + k]; sh1[t] += sh1[t + k]; sh2[t] += sh2[t + k]; }
        __syncthreads();
    }
    if (t == 0) {
        if (r < M) {
            ws[WS_SM + r]  = (float)sh0[0];
            ws[WS_NM2 + r] = (float)sh1[0];
            ws[WS_KX + r]  = (float)sh2[0];
        } else {
            ws[WS_SX]  = (float)sh0[0];
            ws[WS_NX2] = (float)sh1[0];
        }
    }
}

// ---- K3: block i — derived stats (fused) + Gram row + A1 + s[a,i] ----
__global__ __launch_bounds__(256) void k3_s(const float* __restrict__ mem,
                                            float* __restrict__ ws) {
    const int i = blockIdx.x;
    const int a = threadIdx.x;

    // per-a derived stats (recomputed in every block — cheap, L2-cached)
    const double nx   = fmax(sqrt(fmax((double)ws[WS_NX2], 0.0)), EPS);
    const double Sx   = (double)ws[WS_SX];
    const double Sm_a = (double)ws[WS_SM + a];
    const double nm2a = (double)ws[WS_NM2 + a];
    const double kx_a = (double)ws[WS_KX + a];
    const double nmsa = fmax(sqrt(fmax(nm2a, 0.0)), EPS);
    const double mx_a = kx_a / (nmsa * nx);
    const double maska = (mx_a > THRESH) ? 1.0 : 0.0;
    const double w_a = maska / nmsa;
    ws[WS_MASK + a] = (float)maska;   // same value from every block — benign

    // stage row i into LDS (float4)
    __shared__ vfloat4 lrow4[D4];
    if (a < D4) lrow4[a] = ((const vfloat4*)mem)[(size_t)i * D4 + a];
    __syncthreads();

    // g[a] = dot(mem_i, mem_a) via chunked-transposed memT: coalesced float4 loads
    const vfloat4* memT4 = (const vfloat4*)(ws + WS_MEMT);
    float acc0 = 0.f, acc1 = 0.f, acc2 = 0.f, acc3 = 0.f;
    for (int dq = 0; dq < D4; dq += 4) {
        vfloat4 v0 = memT4[(dq + 0) * M + a]; vfloat4 l0 = lrow4[dq + 0];
        vfloat4 v1 = memT4[(dq + 1) * M + a]; vfloat4 l1 = lrow4[dq + 1];
        vfloat4 v2 = memT4[(dq + 2) * M + a]; vfloat4 l2 = lrow4[dq + 2];
        vfloat4 v3 = memT4[(dq + 3) * M + a]; vfloat4 l3 = lrow4[dq + 3];
        acc0 += v0.x * l0.x + v0.y * l0.y + v0.z * l0.z + v0.w * l0.w;
        acc1 += v1.x * l1.x + v1.y * l1.y + v1.z * l1.z + v1.w * l1.w;
        acc2 += v2.x * l2.x + v2.y * l2.y + v2.z * l2.z + v2.w * l2.w;
        acc3 += v3.x * l3.x + v3.y * l3.y + v3.z * l3.z + v3.w * l3.w;
    }
    const double g = (double)((acc0 + acc1) + (acc2 + acc3));

    // block reductions: cnt, A2, A1[i] = sum_a w_a * g[a]
    __shared__ double shc[256], sha[256], shr[256];
    shc[a] = maska;
    sha[a] = maska * Sm_a / nmsa;
    shr[a] = w_a * g;
    __syncthreads();
    for (int k = 128; k > 0; k >>= 1) {
        if (a < k) { shc[a] += shc[a + k]; sha[a] += sha[a + k]; shr[a] += shr[a + k]; }
        __syncthreads();
    }
    const double cnt = shc[0];
    const double A2  = sha[0];
    const double A1  = shr[0];

    // i-uniform stats
    const double nm2i = (double)ws[WS_NM2 + i];
    const double Smi  = (double)ws[WS_SM + i];
    const double kxi  = (double)ws[WS_KX + i];
    const double nmsi = fmax(sqrt(fmax(nm2i, 0.0)), EPS);
    const double mxi  = kxi / (nmsi * nx);

    const double c = g / (nmsa * nmsi) + mxi;
    const double nkp = sqrt(fmax(nm2i + 2.0 * c * Smi + (double)D * c * c, EPS * EPS));
    const double cos_kp_x = (kxi + c * Sx) / (nkp * nx);
    const double mean_cos_km = (cnt > 0.0) ? (A1 + c * A2) / (nkp * fmax(cnt, 1.0)) : 0.0;

    ws[WS_ST + i * M + a] = (float)(c + cos_kp_x + mean_cos_km);
}

// ---- K4: out[a,i,:] = mask[a] ? mem[i,:] + s[a,i] + noise[a,i,:] : 0 ----
// grid (8, 256): block = (i-slab of 32 rows, a). 192 threads, 32 streaming iters.
__global__ __launch_bounds__(D4) void k4_final(const float* __restrict__ mem,
                                               const float* __restrict__ noise,
                                               const float* __restrict__ ws,
                                               float* __restrict__ out) {
    const int a  = blockIdx.y;
    const int i0 = blockIdx.x * 32;
    const int t  = threadIdx.x;   // 0..191

    const vfloat4* mem4   = (const vfloat4*)mem;
    const vfloat4* noise4 = (const vfloat4*)noise;
    vfloat4* out4         = (vfloat4*)out;
    const size_t base = ((size_t)a * M + i0) * D4 + t;

    if (ws[WS_MASK + a] != 0.0f) {
        __shared__ float ssh[32];
        if (t < 32) ssh[t] = ws[WS_ST + (i0 + t) * M + a];
        __syncthreads();
        #pragma unroll 4
        for (int il = 0; il < 32; ++il) {
            const float s = ssh[il];
            vfloat4 m = mem4[(size_t)(i0 + il) * D4 + t];
            vfloat4 n = __builtin_nontemporal_load(noise4 + base + (size_t)il * D4);
            vfloat4 o;
            o.x = m.x + s + n.x;
            o.y = m.y + s + n.y;
            o.z = m.z + s + n.z;
            o.w = m.w + s + n.w;
            __builtin_nontemporal_store(o, out4 + base + (size_t)il * D4);
        }
    } else {
        const vfloat4 z = (vfloat4){0.f, 0.f, 0.f, 0.f};
        #pragma unroll 8
        for (int il = 0; il < 32; ++il)
            __builtin_nontemporal_store(z, out4 + base + (size_t)il * D4);
    }
}

extern "C" void kernel_launch(void* const* d_in, const int* in_sizes, int n_in,
                              void* d_out, int out_size, void* d_ws, size_t ws_size,
                              hipStream_t stream) {
    const float* x     = (const float*)d_in[0];   // [1, D]
    const float* mem   = (const float*)d_in[1];   // [M, D]
    const float* noise = (const float*)d_in[2];   // [M, M, D]
    float* out = (float*)d_out;
    float* ws  = (float*)d_ws;

    k1_stats_transpose<<<dim3(M + 1), dim3(256), 0, stream>>>(x, mem, ws);
    k3_s<<<dim3(M), dim3(256), 0, stream>>>(mem, ws);
    k4_final<<<dim3(8, M), dim3(D4), 0, stream>>>(mem, noise, ws, out);
}

// Round 4
// 335.477 us; speedup vs baseline: 1.0306x; 1.0306x over previous
//
#include <hip/hip_runtime.h>
#include <hip/hip_bf16.h>
#include <math.h>

#define M 256
#define D 768
#define D4 (D/4)          // 192
#define THRESH 0.3
#define EPS 1e-8

typedef float vfloat4 __attribute__((ext_vector_type(4)));

// Workspace layout (floats):
#define WS_SM    0      // [256] row sums of mem
#define WS_NM2   256    // [256] row sumsq
#define WS_KX    512    // [256] dot(mem_i, x)
#define WS_MASK  768    // [256] mask (written by k3 block 0)
#define WS_SX    1024
#define WS_NX2   1025
#define WS_MEMT  2048                 // [D*M] mem transposed, float4-chunked:
                                      // element (d,r) at (d>>2)*1024 + r*4 + (d&3)
#define WS_ST    (2048 + D * M)       // [M*M] sT[i*M + a] = s[a,i]

// ---- K1: per-row stats (blocks 0..255) + x stats (block 256) + chunked transpose ----
__global__ __launch_bounds__(256) void k1_stats_transpose(const float* __restrict__ x,
                                                          const float* __restrict__ mem,
                                                          float* __restrict__ ws) {
    const int r = blockIdx.x;
    const int t = threadIdx.x;
    const float* row = (r < M) ? (mem + (size_t)r * D) : x;

    double s = 0.0, sq = 0.0, dt = 0.0;
    for (int d = t; d < D; d += 256) {
        float mf = row[d];
        double m = (double)mf;
        double xv = (double)x[d];
        s += m; sq += m * m; dt += m * xv;
        if (r < M) ws[WS_MEMT + (d >> 2) * (M * 4) + r * 4 + (d & 3)] = mf;
    }
    __shared__ double sh0[256], sh1[256], sh2[256];
    sh0[t] = s; sh1[t] = sq; sh2[t] = dt;
    __syncthreads();
    for (int k = 128; k > 0; k >>= 1) {
        if (t < k) { sh0[t] += sh0[t + k]; sh1[t] += sh1[t + k]; sh2[t] += sh2[t + k]; }
        __syncthreads();
    }
    if (t == 0) {
        if (r < M) {
            ws[WS_SM + r]  = (float)sh0[0];
            ws[WS_NM2 + r] = (float)sh1[0];
            ws[WS_KX + r]  = (float)sh2[0];
        } else {
            ws[WS_SX]  = (float)sh0[0];
            ws[WS_NX2] = (float)sh1[0];
        }
    }
}

// ---- K3: block i — mask (double, threshold-safe) + overlapped zero-fill of
//          inactive out rows (column i) + Gram row + reductions + s[a,i] ----
__global__ __launch_bounds__(256) void k3_s(const float* __restrict__ mem,
                                            float* __restrict__ ws,
                                            float* __restrict__ out) {
    const int i = blockIdx.x;
    const int a = threadIdx.x;

    // mask in double (threshold crossing must match reference exactly)
    const double nxd   = fmax(sqrt(fmax((double)ws[WS_NX2], 0.0)), EPS);
    const double nm2ad = (double)ws[WS_NM2 + a];
    const double nmsad = fmax(sqrt(fmax(nm2ad, 0.0)), EPS);
    const double mxad  = (double)ws[WS_KX + a] / (nmsad * nxd);
    const float maska = (mxad > THRESH) ? 1.0f : 0.0f;
    const float nmsa  = (float)nmsad;
    if (i == 0) ws[WS_MASK + a] = maska;

    __shared__ float shmask[M];
    __shared__ vfloat4 lrow4[D4];
    shmask[a] = maska;
    if (a < D4) lrow4[a] = ((const vfloat4*)mem)[(size_t)i * D4 + a];
    __syncthreads();

    // fire-and-forget zero-fill for inactive rows of column i (overlaps compute)
    if (a < D4) {
        vfloat4* out4 = (vfloat4*)out;
        const vfloat4 z = (vfloat4){0.f, 0.f, 0.f, 0.f};
        for (int ap = 0; ap < M; ++ap) {
            if (shmask[ap] == 0.0f)
                __builtin_nontemporal_store(z, out4 + ((size_t)ap * M + i) * D4 + a);
        }
    }

    // g[a] = dot(mem_i, mem_a) via chunked-transposed memT (coalesced float4 L2 loads)
    const vfloat4* memT4 = (const vfloat4*)(ws + WS_MEMT);
    float acc0 = 0.f, acc1 = 0.f, acc2 = 0.f, acc3 = 0.f;
    for (int dq = 0; dq < D4; dq += 4) {
        vfloat4 v0 = memT4[(dq + 0) * M + a]; vfloat4 l0 = lrow4[dq + 0];
        vfloat4 v1 = memT4[(dq + 1) * M + a]; vfloat4 l1 = lrow4[dq + 1];
        vfloat4 v2 = memT4[(dq + 2) * M + a]; vfloat4 l2 = lrow4[dq + 2];
        vfloat4 v3 = memT4[(dq + 3) * M + a]; vfloat4 l3 = lrow4[dq + 3];
        acc0 += v0.x * l0.x + v0.y * l0.y + v0.z * l0.z + v0.w * l0.w;
        acc1 += v1.x * l1.x + v1.y * l1.y + v1.z * l1.z + v1.w * l1.w;
        acc2 += v2.x * l2.x + v2.y * l2.y + v2.z * l2.z + v2.w * l2.w;
        acc3 += v3.x * l3.x + v3.y * l3.y + v3.z * l3.z + v3.w * l3.w;
    }
    const float g = (acc0 + acc1) + (acc2 + acc3);

    // float reductions: cnt, A2, A1[i] = sum_a (mask_a/nms_a) * g[a]
    __shared__ float shc[M], sha[M], shr[M];
    shc[a] = maska;
    sha[a] = maska * ws[WS_SM + a] / nmsa;
    shr[a] = (maska / nmsa) * g;
    __syncthreads();
    for (int k = 128; k > 0; k >>= 1) {
        if (a < k) { shc[a] += shc[a + k]; sha[a] += sha[a + k]; shr[a] += shr[a + k]; }
        __syncthreads();
    }
    const float cnt = shc[0];
    const float A2  = sha[0];
    const float A1  = shr[0];

    // i-uniform stats (float — output tolerance is generous)
    const float nm2i = ws[WS_NM2 + i];
    const float Smi  = ws[WS_SM + i];
    const float kxi  = ws[WS_KX + i];
    const float nmsi = fmaxf(sqrtf(fmaxf(nm2i, 0.f)), 1e-8f);
    const float nx   = (float)nxd;
    const float Sx   = ws[WS_SX];
    const float mxi  = kxi / (nmsi * nx);

    const float c = g / (nmsa * nmsi) + mxi;
    const float nkp = sqrtf(fmaxf(nm2i + 2.f * c * Smi + (float)D * c * c, 1e-16f));
    const float cos_kp_x = (kxi + c * Sx) / (nkp * nx);
    const float mean_cos_km = (cnt > 0.f) ? (A1 + c * A2) / (nkp * fmaxf(cnt, 1.f)) : 0.f;

    ws[WS_ST + i * M + a] = c + cos_kp_x + mean_cos_km;
}

// ---- K4: active rows only — out[a,i,:] = mem[i,:] + s[a,i] + noise[a,i,:] ----
// grid (16, 256): block = (i-slab of 16 rows, a); inactive a exits immediately.
__global__ __launch_bounds__(D4) void k4_final(const float* __restrict__ mem,
                                               const float* __restrict__ noise,
                                               const float* __restrict__ ws,
                                               float* __restrict__ out) {
    const int a = blockIdx.y;
    if (ws[WS_MASK + a] == 0.0f) return;
    const int i0 = blockIdx.x * 16;
    const int t  = threadIdx.x;   // 0..191

    const vfloat4* mem4   = (const vfloat4*)mem;
    const vfloat4* noise4 = (const vfloat4*)noise;
    vfloat4* out4         = (vfloat4*)out;
    const size_t base = ((size_t)a * M + i0) * D4 + t;

    __shared__ float ssh[16];
    if (t < 16) ssh[t] = ws[WS_ST + (i0 + t) * M + a];
    __syncthreads();

    #pragma unroll 4
    for (int il = 0; il < 16; ++il) {
        const float s = ssh[il];
        vfloat4 m = mem4[(size_t)(i0 + il) * D4 + t];
        vfloat4 n = __builtin_nontemporal_load(noise4 + base + (size_t)il * D4);
        vfloat4 o;
        o.x = m.x + s + n.x;
        o.y = m.y + s + n.y;
        o.z = m.z + s + n.z;
        o.w = m.w + s + n.w;
        __builtin_nontemporal_store(o, out4 + base + (size_t)il * D4);
    }
}

extern "C" void kernel_launch(void* const* d_in, const int* in_sizes, int n_in,
                              void* d_out, int out_size, void* d_ws, size_t ws_size,
                              hipStream_t stream) {
    const float* x     = (const float*)d_in[0];   // [1, D]
    const float* mem   = (const float*)d_in[1];   // [M, D]
    const float* noise = (const float*)d_in[2];   // [M, M, D]
    float* out = (float*)d_out;
    float* ws  = (float*)d_ws;

    k1_stats_transpose<<<dim3(M + 1), dim3(256), 0, stream>>>(x, mem, ws);
    k3_s<<<dim3(M), dim3(256), 0, stream>>>(mem, ws, out);
    k4_final<<<dim3(16, M), dim3(D4), 0, stream>>>(mem, noise, ws, out);
}